// Round 1
// baseline (161.903 us; speedup 1.0000x reference)
//
#include <hip/hip_runtime.h>
#include <math.h>

// RMSELoss(early=1, gap=0.5, late=2), train=True path:
//   d = t - x
//   v = d>=0.5 ? d^3 : (d<0 ? d^4 : 1)
//   out = sqrt(mean(v))

__device__ __forceinline__ float vfun(float d) {
    float d2 = d * d;
    float e  = d2 * d;   // d^(2+early) = d^3
    float l  = d2 * d2;  // d^(2+late)  = d^4
    // predicated select, no divergence
    return d >= 0.5f ? e : (d < 0.0f ? l : 1.0f);
}

__global__ __launch_bounds__(256) void rmse_partial(
        const float4* __restrict__ x4,
        const float4* __restrict__ t4,
        const float*  __restrict__ x,
        const float*  __restrict__ t,
        float* __restrict__ sum_ws,
        int n4, int n) {
    int idx    = blockIdx.x * blockDim.x + threadIdx.x;
    int stride = gridDim.x * blockDim.x;

    float acc = 0.0f;
    for (int i = idx; i < n4; i += stride) {
        float4 a = x4[i];
        float4 b = t4[i];
        acc += vfun(b.x - a.x);
        acc += vfun(b.y - a.y);
        acc += vfun(b.z - a.z);
        acc += vfun(b.w - a.w);
    }
    // scalar tail (n not divisible by 4) — thread 0 of block 0 only
    if (idx == 0) {
        for (int i = n4 * 4; i < n; ++i) acc += vfun(t[i] - x[i]);
    }

    // wave-64 reduction
    #pragma unroll
    for (int off = 32; off > 0; off >>= 1)
        acc += __shfl_down(acc, off, 64);

    __shared__ float smem[4];  // 256 threads = 4 waves
    int lane = threadIdx.x & 63;
    int wave = threadIdx.x >> 6;
    if (lane == 0) smem[wave] = acc;
    __syncthreads();
    if (threadIdx.x == 0) {
        float s = smem[0] + smem[1] + smem[2] + smem[3];
        atomicAdd(sum_ws, s);  // device-scope by default on CDNA
    }
}

__global__ void rmse_final(const float* __restrict__ sum_ws,
                           float* __restrict__ out, float inv_n) {
    out[0] = sqrtf(sum_ws[0] * inv_n);
}

extern "C" void kernel_launch(void* const* d_in, const int* in_sizes, int n_in,
                              void* d_out, int out_size, void* d_ws, size_t ws_size,
                              hipStream_t stream) {
    const float* x = (const float*)d_in[0];   // inputs
    const float* t = (const float*)d_in[1];   // targets
    float* out = (float*)d_out;
    float* ws  = (float*)d_ws;

    int n  = in_sizes[0];
    int n4 = n / 4;

    // ws is poisoned 0xAA before every call — zero the accumulator.
    hipMemsetAsync(ws, 0, sizeof(float), stream);

    // 2048 blocks x 256 threads = 512K threads, 32 elems/thread at N=16Mi.
    // 8 waves/CU-worth of oversubscription across 256 CUs for latency hiding.
    int grid = 2048;
    rmse_partial<<<grid, 256, 0, stream>>>(
        (const float4*)x, (const float4*)t, x, t, ws, n4, n);

    rmse_final<<<1, 1, 0, stream>>>(ws, out, 1.0f / (float)n);
}

// Round 2
// 144.464 us; speedup vs baseline: 1.1207x; 1.1207x over previous
//
#include <hip/hip_runtime.h>
#include <math.h>

// RMSELoss(early=1, gap=0.5, late=2), train=True path:
//   d = t - x
//   v = d>=0.5 ? d^3 : (d<0 ? d^4 : 1)
//   out = sqrt(mean(v))

#define BLOCK 256
#define GRID  2048
#define NWAVE (BLOCK / 64)

__device__ __forceinline__ float vfun(float d) {
    float d2 = d * d;
    float e  = d2 * d;   // d^3
    float l  = d2 * d2;  // d^4
    return d >= 0.5f ? e : (d < 0.0f ? l : 1.0f);
}

__device__ __forceinline__ float vfun4(float4 a, float4 b) {
    return vfun(b.x - a.x) + vfun(b.y - a.y) + vfun(b.z - a.z) + vfun(b.w - a.w);
}

__global__ __launch_bounds__(BLOCK) void rmse_partial(
        const float4* __restrict__ x4,
        const float4* __restrict__ t4,
        const float*  __restrict__ x,
        const float*  __restrict__ t,
        float* __restrict__ block_sums,
        int n4, int n) {
    int idx    = blockIdx.x * blockDim.x + threadIdx.x;
    int stride = gridDim.x * blockDim.x;

    float acc = 0.0f;
    int i = idx;

    // Unrolled x4: 8 independent float4 loads in flight before any use.
    // At N=16Mi, n4=4Mi, stride=512K: exactly 2 unrolled iterations, no remainder.
    for (; i + 3 * stride < n4; i += 4 * stride) {
        float4 a0 = x4[i];
        float4 a1 = x4[i + stride];
        float4 a2 = x4[i + 2 * stride];
        float4 a3 = x4[i + 3 * stride];
        float4 b0 = t4[i];
        float4 b1 = t4[i + stride];
        float4 b2 = t4[i + 2 * stride];
        float4 b3 = t4[i + 3 * stride];
        acc += vfun4(a0, b0);
        acc += vfun4(a1, b1);
        acc += vfun4(a2, b2);
        acc += vfun4(a3, b3);
    }
    // remainder (generality; empty at N=16Mi)
    for (; i < n4; i += stride) {
        acc += vfun4(x4[i], t4[i]);
    }
    // scalar tail (n % 4)
    if (idx == 0) {
        for (int j = n4 * 4; j < n; ++j) acc += vfun(t[j] - x[j]);
    }

    // wave-64 reduction
    #pragma unroll
    for (int off = 32; off > 0; off >>= 1)
        acc += __shfl_down(acc, off, 64);

    __shared__ float smem[NWAVE];
    int lane = threadIdx.x & 63;
    int wave = threadIdx.x >> 6;
    if (lane == 0) smem[wave] = acc;
    __syncthreads();
    if (threadIdx.x == 0) {
        float s = 0.0f;
        #pragma unroll
        for (int w = 0; w < NWAVE; ++w) s += smem[w];
        block_sums[blockIdx.x] = s;   // every slot written — no memset needed
    }
}

__global__ __launch_bounds__(BLOCK) void rmse_final(
        const float* __restrict__ block_sums,
        float* __restrict__ out, float inv_n, int nb) {
    float s = 0.0f;
    for (int i = threadIdx.x; i < nb; i += BLOCK) s += block_sums[i];

    #pragma unroll
    for (int off = 32; off > 0; off >>= 1)
        s += __shfl_down(s, off, 64);

    __shared__ float smem[NWAVE];
    int lane = threadIdx.x & 63;
    int wave = threadIdx.x >> 6;
    if (lane == 0) smem[wave] = s;
    __syncthreads();
    if (threadIdx.x == 0) {
        float tot = 0.0f;
        #pragma unroll
        for (int w = 0; w < NWAVE; ++w) tot += smem[w];
        out[0] = sqrtf(tot * inv_n);
    }
}

extern "C" void kernel_launch(void* const* d_in, const int* in_sizes, int n_in,
                              void* d_out, int out_size, void* d_ws, size_t ws_size,
                              hipStream_t stream) {
    const float* x = (const float*)d_in[0];   // inputs
    const float* t = (const float*)d_in[1];   // targets
    float* out = (float*)d_out;
    float* ws  = (float*)d_ws;                // GRID floats of partial sums

    int n  = in_sizes[0];
    int n4 = n / 4;

    rmse_partial<<<GRID, BLOCK, 0, stream>>>(
        (const float4*)x, (const float4*)t, x, t, ws, n4, n);

    rmse_final<<<1, BLOCK, 0, stream>>>(ws, out, 1.0f / (float)n, GRID);
}